// Round 12
// baseline (235.769 us; speedup 1.0000x reference)
//
#include <hip/hip_runtime.h>
#include <hip/hip_bf16.h>
#include <cstdint>

typedef __bf16 bf16;
typedef __bf16 bf16x8 __attribute__((ext_vector_type(8)));
typedef float f32x4 __attribute__((ext_vector_type(4)));

#define MFMA16(A, B, C) __builtin_amdgcn_mfma_f32_16x16x32_bf16((A), (B), (C), 0, 0, 0)

// async global->LDS 16B DMA; LDS dest must be wave-uniform base + lane*16
__device__ __forceinline__ void async16(const bf16* g, bf16* l) {
    __builtin_amdgcn_global_load_lds(
        (const __attribute__((address_space(1))) void*)g,
        (__attribute__((address_space(3))) void*)l, 16, 0, 0);
}

// ---------------------------------------------------------------------------
// fused f32 -> bf16 convert for all three inputs (one launch)
// ---------------------------------------------------------------------------
__global__ void cvt_all(const float* __restrict__ x, const float* __restrict__ wq,
                        const float* __restrict__ wo, bf16* __restrict__ xb,
                        bf16* __restrict__ wqb, bf16* __restrict__ wob) {
    const int bid = blockIdx.x;
    const float* s;
    bf16* d;
    int off;
    if (bid < 4096)      { s = x;  d = xb;  off = bid; }
    else if (bid < 5632) { s = wq; d = wqb; off = bid - 4096; }
    else                 { s = wo; d = wob; off = bid - 5632; }
    const size_t i = ((size_t)off * 256 + threadIdx.x) * 8;
    const float4 a = *(const float4*)(s + i);
    const float4 b2 = *(const float4*)(s + i + 4);
    bf16x8 r;
    r[0] = (bf16)a.x; r[1] = (bf16)a.y; r[2] = (bf16)a.z; r[3] = (bf16)a.w;
    r[4] = (bf16)b2.x; r[5] = (bf16)b2.y; r[6] = (bf16)b2.z; r[7] = (bf16)b2.w;
    *(bf16x8*)(d + i) = r;
}

// ---------------------------------------------------------------------------
// NT GEMM, pure bf16, async global_load_lds staging (m97 structure, proven).
// 128x128 tile, BK=64, 256 threads (4 waves, 2x2 wave grid, 4x4 16x16 accs).
// __launch_bounds__(256, 4): 4 blocks/CU (LDS 4x32K=128K<=160K, VGPR 76<<128
// cap -> codegen unchanged). The kernel is latency-bound at the barrier
// drain (MfmaUtil 28%); the 4th resident block adds TLP to hide it, and the
// QKV grid (1536) goes from 2 occupancy-rounds to 1.5.
// MODE 0 (QKV): each block's n-range is purely Q, K, or V.
//   Q/K blocks: scatter epilogue to (B,H,T,64) bf16.
//   V blocks (n0>=2048): LDS-transpose epilogue writes Vt (B,H,64,T) bf16
//   directly -> standalone vtrans kernel eliminated.
// MODE 1: plain row-major f32 store to O0 (ld = N)
// ---------------------------------------------------------------------------
template <int MODE>
__launch_bounds__(256, 4)
__global__ void gemm_nt(const bf16* __restrict__ A, const bf16* __restrict__ Bm,
                        void* __restrict__ O0, bf16* __restrict__ O1,
                        bf16* __restrict__ O2, int N, int K) {
    __shared__ alignas(16) bf16 SM[2][128 * 64];
    bf16* const As = SM[0];
    bf16* const Bs = SM[1];

    const int t = threadIdx.x;
    const int w = t >> 6, l = t & 63, quad = l >> 4, l15 = l & 15;
    const int wm = w & 1, wn = w >> 1;

    // XCD swizzle (nwg % 8 == 0 for both launches: 1536, 512)
    const int gx = (int)gridDim.x;
    const int nwg = gx * (int)gridDim.y;
    const int wg0 = (int)blockIdx.y * gx + (int)blockIdx.x;
    const int wg = (wg0 & 7) * (nwg >> 3) + (wg0 >> 3);
    const int m0 = (wg / gx) * 128, n0 = (wg % gx) * 128;

    f32x4 acc[4][4] = {};

    const int srow = t >> 3, sch = t & 7;
    const bf16* ga = A + (size_t)(m0 + srow) * K + sch * 8;
    const bf16* gb = Bm + (size_t)(n0 + srow) * K + sch * 8;

    for (int kt = 0; kt < K; kt += 64) {
        __syncthreads();
#pragma unroll
        for (int i = 0; i < 4; i++) {
            async16(ga + (size_t)i * 32 * K + kt, &As[(i * 256 + t) * 8]);
            async16(gb + (size_t)i * 32 * K + kt, &Bs[(i * 256 + t) * 8]);
        }
        __syncthreads();

#pragma unroll
        for (int s = 0; s < 2; s++) {
            bf16x8 af[4], bfr[4];
#pragma unroll
            for (int im = 0; im < 4; im++)
                af[im] = *(const bf16x8*)&As[(wm * 64 + im * 16 + l15) * 64 + s * 32 + quad * 8];
#pragma unroll
            for (int in = 0; in < 4; in++)
                bfr[in] = *(const bf16x8*)&Bs[(wn * 64 + in * 16 + l15) * 64 + s * 32 + quad * 8];
#pragma unroll
            for (int im = 0; im < 4; im++)
#pragma unroll
                for (int in = 0; in < 4; in++)
                    acc[im][in] = MFMA16(af[im], bfr[in], acc[im][in]);
        }
    }

    if (MODE == 0) {
        if (n0 >= 2048) {
            // ---- V block: transpose via LDS, write Vt (B,H,64,T) ----
            __syncthreads();  // main-loop LDS reads done
            bf16* const Ts = &SM[0][0];  // 128 cols x 128 rows (16384 elems)
            // write acc: phys elem = col*128 + (row ^ ((col&7)<<3))
#pragma unroll
            for (int in = 0; in < 4; in++) {
                const int col = wn * 64 + in * 16 + l15;
                const int cx = (col & 7) << 3;
#pragma unroll
                for (int im = 0; im < 4; im++) {
                    const int row0 = (wm * 64 + im * 16 + quad * 4) ^ cx;
#pragma unroll
                    for (int r = 0; r < 4; r++)
                        Ts[col * 128 + row0 + r] = (bf16)acc[im][in][r];
                }
            }
            __syncthreads();
            bf16* VtOut = O2;
            const int bb = m0 >> 11, tt0 = m0 & 2047;
            const int c0 = n0 - 2048;
#pragma unroll
            for (int p = 0; p < 8; p++) {
                const int col = p * 16 + w * 4 + (l >> 4);  // 0..127
                const int chunk = l & 15;                   // 8-row chunk
                const int physc = ((chunk ^ (col & 7)) & 7) + (chunk & 8);
                const bf16x8 v = *(const bf16x8*)&Ts[col * 128 + physc * 8];
                const int cg = c0 + col, h = cg >> 6, d = cg & 63;
                *(bf16x8*)&VtOut[((size_t)(bb * 16 + h) * 64 + d) * 2048 + tt0 + chunk * 8] = v;
            }
        } else {
            // ---- Q/K block: scatter epilogue ----
            bf16* Q0 = (bf16*)O0;
#pragma unroll
            for (int in = 0; in < 4; in++) {
                const int n = n0 + wn * 64 + in * 16;
                const int sel = n >> 10;
                const int c = n & 1023;
                const int h = c >> 6;
                const int dd = c & 63;
                bf16* dst = (sel == 0) ? Q0 : O1;
#pragma unroll
                for (int im = 0; im < 4; im++) {
#pragma unroll
                    for (int r = 0; r < 4; r++) {
                        const int m = m0 + wm * 64 + im * 16 + quad * 4 + r;
                        const int b = m >> 11, tt = m & 2047;
                        dst[((size_t)(b * 16 + h) * 2048 + tt) * 64 + dd + l15] =
                            (bf16)acc[im][in][r];
                    }
                }
            }
        }
    } else {
        float* Of = (float*)O0;
#pragma unroll
        for (int im = 0; im < 4; im++) {
#pragma unroll
            for (int in = 0; in < 4; in++) {
#pragma unroll
                for (int r = 0; r < 4; r++) {
                    const int m = m0 + wm * 64 + im * 16 + quad * 4 + r;
                    const int n = n0 + wn * 64 + in * 16 + l15;
                    Of[(size_t)m * N + n] = acc[im][in][r];
                }
            }
        }
    }
}

// ---------------------------------------------------------------------------
// Causal flash attention, merged-pair K-loop (R8 structure — measured best).
// Block owns Q-tiles qt0=pair, qt1=31-pair of one (b,h); ONE kt-loop 0..qt1
// (half0 active while kt<=qt0). S computed transposed (A=K w/ permuted row
// map, B=Q) so each lane's S^T regs are exactly the PV A-frags. No-reference
// softmax (global 2^c cancels in p/sum); raw v_exp_f32; li row-sums ride the
// MFMA pipe (B = ones) in the same C/D row layout as O. Q pre-scaled.
// T14 async-STAGE: next tile's K/V loads issued before compute.
// Single-buffer LDS, 2 barriers/iter — probed neighbors all regressed:
//   read-swizzle (R7: conflicts UP, +5-10us), zero-LDS (R9: 3x worse,
//   VMEM gather latency-bound), dbuf+setprio (R10: +6us, lockstep loop is
//   the m190 setprio-null case). This config is the local optimum.
// Grid (bh=64, pair=16): 16 pair-blocks of one bh land on the same XCD.
// ---------------------------------------------------------------------------
__launch_bounds__(256, 4)
__global__ void attn_fwd(const bf16* __restrict__ Q, const bf16* __restrict__ Kk,
                         const bf16* __restrict__ Vt, bf16* __restrict__ O) {
    __shared__ alignas(16) bf16 Ks[64 * 72];      // K tile  [kpos][d], ld=72
    __shared__ alignas(16) bf16 Vs[64 * 72];      // Vt tile [d][kpos], ld=72

    const int t = threadIdx.x, w = t >> 6, l = t & 63;
    const int quad = l >> 4, l15 = l & 15;
    const int bh = blockIdx.x, pair = blockIdx.y;   // bh fastest -> same-XCD pairs
    const int b = bh >> 4, h = bh & 15;
    const int sr = t >> 3, sc = t & 7;

    const bf16* Qbase = Q + (size_t)bh * 2048 * 64;
    const bf16* Kbase = Kk + (size_t)bh * 2048 * 64;
    const bf16* Vbase = Vt + (size_t)bh * 64 * 2048;

    const int qt0 = pair, qt1 = 31 - pair;

    // permuted K-row map: tile nt, lane-m l15 -> local K row
    int kr[4];
#pragma unroll
    for (int nt = 0; nt < 4; nt++)
        kr[nt] = (nt >> 1) * 32 + (l15 >> 2) * 8 + (nt & 1) * 4 + (l15 & 3);

    // Q B-frags for both halves, pre-scaled by log2(e)/8
    bf16x8 aq[2][2];
#pragma unroll
    for (int hf = 0; hf < 2; hf++) {
        const int qrow = (hf ? qt1 : qt0) * 64 + w * 16 + l15;
        aq[hf][0] = *(const bf16x8*)&Qbase[(size_t)qrow * 64 + quad * 8];
        aq[hf][1] = *(const bf16x8*)&Qbase[(size_t)qrow * 64 + 32 + quad * 8];
#pragma unroll
        for (int j = 0; j < 8; j++) {
            aq[hf][0][j] = aq[hf][0][j] * (bf16)0.1803369f;
            aq[hf][1][j] = aq[hf][1][j] * (bf16)0.1803369f;
        }
    }

    // ones B-frag for the li row-sum MFMA
    bf16x8 ones;
#pragma unroll
    for (int j = 0; j < 8; j++) ones[j] = (bf16)1.0f;

    f32x4 liacc[2] = {};
    f32x4 oa[2][4] = {};

    // prologue: load tile 0 into registers
    bf16x8 rk0 = *(const bf16x8*)&Kbase[(size_t)sr * 64 + sc * 8];
    bf16x8 rk1 = *(const bf16x8*)&Kbase[(size_t)(sr + 32) * 64 + sc * 8];
    bf16x8 rv0 = *(const bf16x8*)&Vbase[(size_t)sr * 2048 + sc * 8];
    bf16x8 rv1 = *(const bf16x8*)&Vbase[(size_t)(sr + 32) * 2048 + sc * 8];

    for (int kt = 0; kt <= qt1; kt++) {
        __syncthreads();  // previous iter's tile reads done
        *(bf16x8*)&Ks[sr * 72 + sc * 8] = rk0;
        *(bf16x8*)&Ks[(sr + 32) * 72 + sc * 8] = rk1;
        *(bf16x8*)&Vs[sr * 72 + sc * 8] = rv0;
        *(bf16x8*)&Vs[(sr + 32) * 72 + sc * 8] = rv1;
        __syncthreads();

        // T14: issue next tile's loads now; latency hides under compute below
        if (kt < qt1) {
            const int kn = kt + 1;
            rk0 = *(const bf16x8*)&Kbase[(size_t)(kn * 64 + sr) * 64 + sc * 8];
            rk1 = *(const bf16x8*)&Kbase[(size_t)(kn * 64 + sr + 32) * 64 + sc * 8];
            rv0 = *(const bf16x8*)&Vbase[(size_t)sr * 2048 + kn * 64 + sc * 8];
            rv1 = *(const bf16x8*)&Vbase[(size_t)(sr + 32) * 2048 + kn * 64 + sc * 8];
        }

        const bool do0 = (kt <= qt0);

        // S^T by nt-pairs; ka frags shared across halves; pack PV A-frags
        bf16x8 ap[2][2];  // [hf][s2]
#pragma unroll
        for (int np = 0; np < 2; np++) {
            bf16x8 ka[2][2];
#pragma unroll
            for (int i = 0; i < 2; i++) {
                ka[i][0] = *(const bf16x8*)&Ks[kr[2 * np + i] * 72 + quad * 8];
                ka[i][1] = *(const bf16x8*)&Ks[kr[2 * np + i] * 72 + 32 + quad * 8];
            }
#pragma unroll
            for (int hf = 0; hf < 2; hf++) {
                if (hf == 0 && !do0) continue;
                const bool diag = (kt == (hf ? qt1 : qt0));
#pragma unroll
                for (int i = 0; i < 2; i++) {
                    f32x4 s = {};
                    s = MFMA16(ka[i][0], aq[hf][0], s);
                    s = MFMA16(ka[i][1], aq[hf][1], s);
                    const int kbase = np * 32 + quad * 8 + i * 4;
#pragma unroll
                    for (int r = 0; r < 4; r++) {
                        float x = s[r];
                        if (diag && (kbase + r) > (w * 16 + l15)) x = -1e30f;
                        ap[hf][np][i * 4 + r] = (bf16)__builtin_amdgcn_exp2f(x);
                    }
                }
            }
        }

        // O += P V : bv frags read once, feed both halves.
#pragma unroll
        for (int s2 = 0; s2 < 2; s2++) {
            if (do0) liacc[0] = MFMA16(ap[0][s2], ones, liacc[0]);
            liacc[1] = MFMA16(ap[1][s2], ones, liacc[1]);
#pragma unroll
            for (int dt = 0; dt < 4; dt++) {
                bf16x8 bv = *(const bf16x8*)&Vs[(dt * 16 + l15) * 72 + s2 * 32 + quad * 8];
                if (do0) oa[0][dt] = MFMA16(ap[0][s2], bv, oa[0][dt]);
                oa[1][dt] = MFMA16(ap[1][s2], bv, oa[1][dt]);
            }
        }
    }

    // epilogue: liacc[hf][r] is already the full row-sum for q-row quad*4+r
#pragma unroll
    for (int hf = 0; hf < 2; hf++) {
        const int qt = hf ? qt1 : qt0;
#pragma unroll
        for (int r = 0; r < 4; r++) {
            const float inv = __builtin_amdgcn_rcpf(liacc[hf][r]);
            const int m = b * 2048 + qt * 64 + w * 16 + quad * 4 + r;
#pragma unroll
            for (int dt = 0; dt < 4; dt++) {
                O[(size_t)m * 1024 + h * 64 + dt * 16 + l15] = (bf16)(oa[hf][dt][r] * inv);
            }
        }
    }
}

// ---------------------------------------------------------------------------
extern "C" void kernel_launch(void* const* d_in, const int* in_sizes, int n_in,
                              void* d_out, int out_size, void* d_ws, size_t ws_size,
                              hipStream_t stream) {
    const float* x = (const float*)d_in[0];     // (8192, 1024) f32
    const float* wqkv = (const float*)d_in[1];  // (3072, 1024) f32
    const float* wo = (const float*)d_in[2];    // (1024, 1024) f32

    const size_t SZ = (size_t)8192 * 1024;
    bf16* xb = (bf16*)d_ws;                 // x bf16; reused as attn output
    bf16* wqb = xb + SZ;                    // W_qkv bf16
    bf16* wob = wqb + (size_t)3072 * 1024;  // W_o bf16
    bf16* Qw = wob + (size_t)1024 * 1024;
    bf16* Kw = Qw + SZ;
    bf16* Vtw = Kw + SZ;                    // Vt (B,H,64,T), written by gemm

    dim3 blk(256);
    cvt_all<<<6144, blk, 0, stream>>>(x, wqkv, wo, xb, wqb, wob);
    // writes Q/K scattered; V blocks write Vt directly (no vtrans kernel)
    gemm_nt<0><<<dim3(24, 64), blk, 0, stream>>>(xb, wqb, Qw, Kw, Vtw, 3072, 1024);
    // attn reads Vt, writes its output into xb (dead after the QKV gemm)
    attn_fwd<<<dim3(64, 16), blk, 0, stream>>>(Qw, Kw, Vtw, xb);
    gemm_nt<1><<<dim3(8, 64), blk, 0, stream>>>(xb, wob, d_out, nullptr, nullptr, 1024, 1024);
}

// Round 13
// 227.405 us; speedup vs baseline: 1.0368x; 1.0368x over previous
//
#include <hip/hip_runtime.h>
#include <hip/hip_bf16.h>
#include <cstdint>

typedef __bf16 bf16;
typedef __bf16 bf16x8 __attribute__((ext_vector_type(8)));
typedef float f32x4 __attribute__((ext_vector_type(4)));

#define MFMA16(A, B, C) __builtin_amdgcn_mfma_f32_16x16x32_bf16((A), (B), (C), 0, 0, 0)

// async global->LDS 16B DMA; LDS dest must be wave-uniform base + lane*16
__device__ __forceinline__ void async16(const bf16* g, bf16* l) {
    __builtin_amdgcn_global_load_lds(
        (const __attribute__((address_space(1))) void*)g,
        (__attribute__((address_space(3))) void*)l, 16, 0, 0);
}

// ---------------------------------------------------------------------------
// fused f32 -> bf16 convert for all three inputs (one launch)
// ---------------------------------------------------------------------------
__global__ void cvt_all(const float* __restrict__ x, const float* __restrict__ wq,
                        const float* __restrict__ wo, bf16* __restrict__ xb,
                        bf16* __restrict__ wqb, bf16* __restrict__ wob) {
    const int bid = blockIdx.x;
    const float* s;
    bf16* d;
    int off;
    if (bid < 4096)      { s = x;  d = xb;  off = bid; }
    else if (bid < 5632) { s = wq; d = wqb; off = bid - 4096; }
    else                 { s = wo; d = wob; off = bid - 5632; }
    const size_t i = ((size_t)off * 256 + threadIdx.x) * 8;
    const float4 a = *(const float4*)(s + i);
    const float4 b2 = *(const float4*)(s + i + 4);
    bf16x8 r;
    r[0] = (bf16)a.x; r[1] = (bf16)a.y; r[2] = (bf16)a.z; r[3] = (bf16)a.w;
    r[4] = (bf16)b2.x; r[5] = (bf16)b2.y; r[6] = (bf16)b2.z; r[7] = (bf16)b2.w;
    *(bf16x8*)(d + i) = r;
}

// ---------------------------------------------------------------------------
// NT GEMM, pure bf16, async global_load_lds staging (m97 structure, proven).
// 128x128 tile, BK=64, 256 threads (4 waves, 2x2 wave grid, 4x4 16x16 accs).
// __launch_bounds__(256,3): best-measured codegen (76 VGPR). (256,4) raised
// occupancy 26->30% but was time-neutral (R12): the barrier-correlated DMA
// drain stalls all resident waves simultaneously — TLP can't hide it.
// Deep-pipeline ports (2/4/8-phase, R3/R4/R6) all regressed at K=1024:
// 16 K-tiles don't amortize the schedule's fixed costs.
// MODE 0 (QKV): each block's n-range is purely Q, K, or V.
//   Q/K blocks: scatter epilogue to (B,H,T,64) bf16.
//   V blocks (n0>=2048): LDS-transpose epilogue writes Vt (B,H,64,T) bf16
//   directly -> standalone vtrans kernel eliminated.
// MODE 1: plain row-major f32 store to O0 (ld = N)
// ---------------------------------------------------------------------------
template <int MODE>
__launch_bounds__(256, 3)
__global__ void gemm_nt(const bf16* __restrict__ A, const bf16* __restrict__ Bm,
                        void* __restrict__ O0, bf16* __restrict__ O1,
                        bf16* __restrict__ O2, int N, int K) {
    __shared__ alignas(16) bf16 SM[2][128 * 64];
    bf16* const As = SM[0];
    bf16* const Bs = SM[1];

    const int t = threadIdx.x;
    const int w = t >> 6, l = t & 63, quad = l >> 4, l15 = l & 15;
    const int wm = w & 1, wn = w >> 1;

    // XCD swizzle (nwg % 8 == 0 for both launches: 1536, 512)
    const int gx = (int)gridDim.x;
    const int nwg = gx * (int)gridDim.y;
    const int wg0 = (int)blockIdx.y * gx + (int)blockIdx.x;
    const int wg = (wg0 & 7) * (nwg >> 3) + (wg0 >> 3);
    const int m0 = (wg / gx) * 128, n0 = (wg % gx) * 128;

    f32x4 acc[4][4] = {};

    const int srow = t >> 3, sch = t & 7;
    const bf16* ga = A + (size_t)(m0 + srow) * K + sch * 8;
    const bf16* gb = Bm + (size_t)(n0 + srow) * K + sch * 8;

    for (int kt = 0; kt < K; kt += 64) {
        __syncthreads();
#pragma unroll
        for (int i = 0; i < 4; i++) {
            async16(ga + (size_t)i * 32 * K + kt, &As[(i * 256 + t) * 8]);
            async16(gb + (size_t)i * 32 * K + kt, &Bs[(i * 256 + t) * 8]);
        }
        __syncthreads();

#pragma unroll
        for (int s = 0; s < 2; s++) {
            bf16x8 af[4], bfr[4];
#pragma unroll
            for (int im = 0; im < 4; im++)
                af[im] = *(const bf16x8*)&As[(wm * 64 + im * 16 + l15) * 64 + s * 32 + quad * 8];
#pragma unroll
            for (int in = 0; in < 4; in++)
                bfr[in] = *(const bf16x8*)&Bs[(wn * 64 + in * 16 + l15) * 64 + s * 32 + quad * 8];
#pragma unroll
            for (int im = 0; im < 4; im++)
#pragma unroll
                for (int in = 0; in < 4; in++)
                    acc[im][in] = MFMA16(af[im], bfr[in], acc[im][in]);
        }
    }

    if (MODE == 0) {
        if (n0 >= 2048) {
            // ---- V block: transpose via LDS, write Vt (B,H,64,T) ----
            __syncthreads();  // main-loop LDS reads done
            bf16* const Ts = &SM[0][0];  // 128 cols x 128 rows (16384 elems)
            // write acc: phys elem = col*128 + (row ^ ((col&7)<<3))
#pragma unroll
            for (int in = 0; in < 4; in++) {
                const int col = wn * 64 + in * 16 + l15;
                const int cx = (col & 7) << 3;
#pragma unroll
                for (int im = 0; im < 4; im++) {
                    const int row0 = (wm * 64 + im * 16 + quad * 4) ^ cx;
#pragma unroll
                    for (int r = 0; r < 4; r++)
                        Ts[col * 128 + row0 + r] = (bf16)acc[im][in][r];
                }
            }
            __syncthreads();
            bf16* VtOut = O2;
            const int bb = m0 >> 11, tt0 = m0 & 2047;
            const int c0 = n0 - 2048;
#pragma unroll
            for (int p = 0; p < 8; p++) {
                const int col = p * 16 + w * 4 + (l >> 4);  // 0..127
                const int chunk = l & 15;                   // 8-row chunk
                const int physc = ((chunk ^ (col & 7)) & 7) + (chunk & 8);
                const bf16x8 v = *(const bf16x8*)&Ts[col * 128 + physc * 8];
                const int cg = c0 + col, h = cg >> 6, d = cg & 63;
                *(bf16x8*)&VtOut[((size_t)(bb * 16 + h) * 64 + d) * 2048 + tt0 + chunk * 8] = v;
            }
        } else {
            // ---- Q/K block: scatter epilogue ----
            bf16* Q0 = (bf16*)O0;
#pragma unroll
            for (int in = 0; in < 4; in++) {
                const int n = n0 + wn * 64 + in * 16;
                const int sel = n >> 10;
                const int c = n & 1023;
                const int h = c >> 6;
                const int dd = c & 63;
                bf16* dst = (sel == 0) ? Q0 : O1;
#pragma unroll
                for (int im = 0; im < 4; im++) {
#pragma unroll
                    for (int r = 0; r < 4; r++) {
                        const int m = m0 + wm * 64 + im * 16 + quad * 4 + r;
                        const int b = m >> 11, tt = m & 2047;
                        dst[((size_t)(b * 16 + h) * 2048 + tt) * 64 + dd + l15] =
                            (bf16)acc[im][in][r];
                    }
                }
            }
        }
    } else {
        float* Of = (float*)O0;
#pragma unroll
        for (int im = 0; im < 4; im++) {
#pragma unroll
            for (int in = 0; in < 4; in++) {
#pragma unroll
                for (int r = 0; r < 4; r++) {
                    const int m = m0 + wm * 64 + im * 16 + quad * 4 + r;
                    const int n = n0 + wn * 64 + in * 16 + l15;
                    Of[(size_t)m * N + n] = acc[im][in][r];
                }
            }
        }
    }
}

// ---------------------------------------------------------------------------
// Causal flash attention, merged-pair K-loop (R8 structure — measured best).
// Block owns Q-tiles qt0=pair, qt1=31-pair of one (b,h); ONE kt-loop 0..qt1
// (half0 active while kt<=qt0). S computed transposed (A=K w/ permuted row
// map, B=Q) so each lane's S^T regs are exactly the PV A-frags. No-reference
// softmax (global 2^c cancels in p/sum); raw v_exp_f32; li row-sums ride the
// MFMA pipe (B = ones) in the same C/D row layout as O. Q pre-scaled.
// T14 async-STAGE: next tile's K/V loads issued before compute.
// Single-buffer LDS, 2 barriers/iter — probed neighbors all regressed:
//   read-swizzle (R7: conflicts UP, +5-10us), zero-LDS (R9: 3x worse,
//   VMEM gather latency-bound), dbuf+setprio (R10: +6us, lockstep loop is
//   the m190 setprio-null case). This config is the local optimum.
// Grid (bh=64, pair=16): 16 pair-blocks of one bh land on the same XCD.
// ---------------------------------------------------------------------------
__launch_bounds__(256, 4)
__global__ void attn_fwd(const bf16* __restrict__ Q, const bf16* __restrict__ Kk,
                         const bf16* __restrict__ Vt, bf16* __restrict__ O) {
    __shared__ alignas(16) bf16 Ks[64 * 72];      // K tile  [kpos][d], ld=72
    __shared__ alignas(16) bf16 Vs[64 * 72];      // Vt tile [d][kpos], ld=72

    const int t = threadIdx.x, w = t >> 6, l = t & 63;
    const int quad = l >> 4, l15 = l & 15;
    const int bh = blockIdx.x, pair = blockIdx.y;   // bh fastest -> same-XCD pairs
    const int b = bh >> 4, h = bh & 15;
    const int sr = t >> 3, sc = t & 7;

    const bf16* Qbase = Q + (size_t)bh * 2048 * 64;
    const bf16* Kbase = Kk + (size_t)bh * 2048 * 64;
    const bf16* Vbase = Vt + (size_t)bh * 64 * 2048;

    const int qt0 = pair, qt1 = 31 - pair;

    // permuted K-row map: tile nt, lane-m l15 -> local K row
    int kr[4];
#pragma unroll
    for (int nt = 0; nt < 4; nt++)
        kr[nt] = (nt >> 1) * 32 + (l15 >> 2) * 8 + (nt & 1) * 4 + (l15 & 3);

    // Q B-frags for both halves, pre-scaled by log2(e)/8
    bf16x8 aq[2][2];
#pragma unroll
    for (int hf = 0; hf < 2; hf++) {
        const int qrow = (hf ? qt1 : qt0) * 64 + w * 16 + l15;
        aq[hf][0] = *(const bf16x8*)&Qbase[(size_t)qrow * 64 + quad * 8];
        aq[hf][1] = *(const bf16x8*)&Qbase[(size_t)qrow * 64 + 32 + quad * 8];
#pragma unroll
        for (int j = 0; j < 8; j++) {
            aq[hf][0][j] = aq[hf][0][j] * (bf16)0.1803369f;
            aq[hf][1][j] = aq[hf][1][j] * (bf16)0.1803369f;
        }
    }

    // ones B-frag for the li row-sum MFMA
    bf16x8 ones;
#pragma unroll
    for (int j = 0; j < 8; j++) ones[j] = (bf16)1.0f;

    f32x4 liacc[2] = {};
    f32x4 oa[2][4] = {};

    // prologue: load tile 0 into registers
    bf16x8 rk0 = *(const bf16x8*)&Kbase[(size_t)sr * 64 + sc * 8];
    bf16x8 rk1 = *(const bf16x8*)&Kbase[(size_t)(sr + 32) * 64 + sc * 8];
    bf16x8 rv0 = *(const bf16x8*)&Vbase[(size_t)sr * 2048 + sc * 8];
    bf16x8 rv1 = *(const bf16x8*)&Vbase[(size_t)(sr + 32) * 2048 + sc * 8];

    for (int kt = 0; kt <= qt1; kt++) {
        __syncthreads();  // previous iter's tile reads done
        *(bf16x8*)&Ks[sr * 72 + sc * 8] = rk0;
        *(bf16x8*)&Ks[(sr + 32) * 72 + sc * 8] = rk1;
        *(bf16x8*)&Vs[sr * 72 + sc * 8] = rv0;
        *(bf16x8*)&Vs[(sr + 32) * 72 + sc * 8] = rv1;
        __syncthreads();

        // T14: issue next tile's loads now; latency hides under compute below
        if (kt < qt1) {
            const int kn = kt + 1;
            rk0 = *(const bf16x8*)&Kbase[(size_t)(kn * 64 + sr) * 64 + sc * 8];
            rk1 = *(const bf16x8*)&Kbase[(size_t)(kn * 64 + sr + 32) * 64 + sc * 8];
            rv0 = *(const bf16x8*)&Vbase[(size_t)sr * 2048 + kn * 64 + sc * 8];
            rv1 = *(const bf16x8*)&Vbase[(size_t)(sr + 32) * 2048 + kn * 64 + sc * 8];
        }

        const bool do0 = (kt <= qt0);

        // S^T by nt-pairs; ka frags shared across halves; pack PV A-frags
        bf16x8 ap[2][2];  // [hf][s2]
#pragma unroll
        for (int np = 0; np < 2; np++) {
            bf16x8 ka[2][2];
#pragma unroll
            for (int i = 0; i < 2; i++) {
                ka[i][0] = *(const bf16x8*)&Ks[kr[2 * np + i] * 72 + quad * 8];
                ka[i][1] = *(const bf16x8*)&Ks[kr[2 * np + i] * 72 + 32 + quad * 8];
            }
#pragma unroll
            for (int hf = 0; hf < 2; hf++) {
                if (hf == 0 && !do0) continue;
                const bool diag = (kt == (hf ? qt1 : qt0));
#pragma unroll
                for (int i = 0; i < 2; i++) {
                    f32x4 s = {};
                    s = MFMA16(ka[i][0], aq[hf][0], s);
                    s = MFMA16(ka[i][1], aq[hf][1], s);
                    const int kbase = np * 32 + quad * 8 + i * 4;
#pragma unroll
                    for (int r = 0; r < 4; r++) {
                        float x = s[r];
                        if (diag && (kbase + r) > (w * 16 + l15)) x = -1e30f;
                        ap[hf][np][i * 4 + r] = (bf16)__builtin_amdgcn_exp2f(x);
                    }
                }
            }
        }

        // O += P V : bv frags read once, feed both halves.
#pragma unroll
        for (int s2 = 0; s2 < 2; s2++) {
            if (do0) liacc[0] = MFMA16(ap[0][s2], ones, liacc[0]);
            liacc[1] = MFMA16(ap[1][s2], ones, liacc[1]);
#pragma unroll
            for (int dt = 0; dt < 4; dt++) {
                bf16x8 bv = *(const bf16x8*)&Vs[(dt * 16 + l15) * 72 + s2 * 32 + quad * 8];
                if (do0) oa[0][dt] = MFMA16(ap[0][s2], bv, oa[0][dt]);
                oa[1][dt] = MFMA16(ap[1][s2], bv, oa[1][dt]);
            }
        }
    }

    // epilogue: liacc[hf][r] is already the full row-sum for q-row quad*4+r
#pragma unroll
    for (int hf = 0; hf < 2; hf++) {
        const int qt = hf ? qt1 : qt0;
#pragma unroll
        for (int r = 0; r < 4; r++) {
            const float inv = __builtin_amdgcn_rcpf(liacc[hf][r]);
            const int m = b * 2048 + qt * 64 + w * 16 + quad * 4 + r;
#pragma unroll
            for (int dt = 0; dt < 4; dt++) {
                O[(size_t)m * 1024 + h * 64 + dt * 16 + l15] = (bf16)(oa[hf][dt][r] * inv);
            }
        }
    }
}

// ---------------------------------------------------------------------------
extern "C" void kernel_launch(void* const* d_in, const int* in_sizes, int n_in,
                              void* d_out, int out_size, void* d_ws, size_t ws_size,
                              hipStream_t stream) {
    const float* x = (const float*)d_in[0];     // (8192, 1024) f32
    const float* wqkv = (const float*)d_in[1];  // (3072, 1024) f32
    const float* wo = (const float*)d_in[2];    // (1024, 1024) f32

    const size_t SZ = (size_t)8192 * 1024;
    bf16* xb = (bf16*)d_ws;                 // x bf16; reused as attn output
    bf16* wqb = xb + SZ;                    // W_qkv bf16
    bf16* wob = wqb + (size_t)3072 * 1024;  // W_o bf16
    bf16* Qw = wob + (size_t)1024 * 1024;
    bf16* Kw = Qw + SZ;
    bf16* Vtw = Kw + SZ;                    // Vt (B,H,64,T), written by gemm

    dim3 blk(256);
    cvt_all<<<6144, blk, 0, stream>>>(x, wqkv, wo, xb, wqb, wob);
    // writes Q/K scattered; V blocks write Vt directly (no vtrans kernel)
    gemm_nt<0><<<dim3(24, 64), blk, 0, stream>>>(xb, wqb, Qw, Kw, Vtw, 3072, 1024);
    // attn reads Vt, writes its output into xb (dead after the QKV gemm)
    attn_fwd<<<dim3(64, 16), blk, 0, stream>>>(Qw, Kw, Vtw, xb);
    gemm_nt<1><<<dim3(8, 64), blk, 0, stream>>>(xb, wob, d_out, nullptr, nullptr, 1024, 1024);
}